// Round 20
// baseline (416.008 us; speedup 1.0000x reference)
//
#include <hip/hip_runtime.h>

#define TSTEPS 2048
#define BATCH  4096
#define HID    4
#define STRIDE (BATCH*HID)    // 16384 floats per timestep slab
#define CH     32             // timesteps per chunk (barrier period)
#define NCHUNK (TSTEPS/CH)    // 64 source chunks
#define NPH    69             // >= NCHUNK+4, = 3*23 for static slot rotation
#define PSTEPS 4096           // probe steps (128 chunks of 32)

// Broadcast component k (0..3) to all 4 lanes of each quad via DPP quad_perm.
#define QB(v,k) __int_as_float(__builtin_amdgcn_update_dpp( \
    0, __float_as_int(v), (k)*0x55, 0xF, 0xF, true))

__device__ __forceinline__ float fast_exp2(float x) {
#if __has_builtin(__builtin_amdgcn_exp2f)
  return __builtin_amdgcn_exp2f(x);
#else
  return exp2f(x);
#endif
}
__device__ __forceinline__ float fast_rcp(float x) {
#if __has_builtin(__builtin_amdgcn_rcpf)
  return __builtin_amdgcn_rcpf(x);
#else
  return 1.0f / x;
#endif
}

// Direct global->LDS 4B load (wave-uniform LDS base + lane*4).
__device__ __forceinline__ void xload(float* ldst, const float* gsrc) {
  __builtin_amdgcn_global_load_lds(
      (const __attribute__((address_space(1))) void*)gsrc,
      (__attribute__((address_space(3))) void*)ldst, 4, 0, 0);
}

// ================= PRODUCTION (r15 keeper, 115 us) ========================
__global__ __launch_bounds__(256) void rnn_pipe4(
    const float* __restrict__ X,    // (T, B, H)
    const float* __restrict__ H0,   // (L, B, H)
    const float* __restrict__ Wih,  // (L, H, H)
    const float* __restrict__ Whh,  // (L, H, H)
    const float* __restrict__ bih,  // (L, H)
    const float* __restrict__ bhh,  // (L, H)
    float* __restrict__ Y)          // (T, B, H)
{
  const int lane = threadIdx.x & 63;
  const int wid  = threadIdx.x >> 6;           // 0 = producer; 1..3 = layers
  const int g    = blockIdx.x * 64 + lane;     // global (b,j) unit
  const int j    = g & 3;
  const float K  = 2.8853900817779268f;        // 2*log2(e)

  __shared__ float iface[3][2][CH][64];        // 48 KB: ai handoff l -> l+1
  __shared__ float xbuf[3][CH][64];            // 24 KB: x staging ring

  float whp[HID], win[HID], cbn = 0.0f, r = 0.0f;
  {
    const int Lt = wid - 1;                    // tail layer
    const int Ln = wid;                        // next-ai layer
    if (wid >= 1) {
#pragma unroll
      for (int k = 0; k < HID; ++k)
        whp[k] = -2.0f * K * Whh[(Lt*HID + j)*HID + k];
      r = 0.5f * (1.0f - H0[Lt*STRIDE + g]);   // h = 1 - 2r
    }
    if (wid <= 2) {
      float wsum = 0.0f;
#pragma unroll
      for (int k = 0; k < HID; ++k) {
        win[k] = K * Wih[(Ln*HID + j)*HID + k];
        wsum  += Whh[(Ln*HID + j)*HID + k];
      }
      cbn = K * (bih[Ln*HID + j] + bhh[Ln*HID + j] + wsum);
    }
  }

  const float* __restrict__ xp = X + g;

  if (wid == 0) {
    __builtin_amdgcn_sched_barrier(0);
    asm volatile("s_waitcnt vmcnt(0)" ::: "memory");
#pragma unroll
    for (int u = 0; u < CH; ++u)
      xload(&xbuf[0][u][0], xp + (size_t)(0*CH + u) * STRIDE);
#pragma unroll
    for (int u = 0; u < CH; ++u)
      xload(&xbuf[1][u][0], xp + (size_t)(1*CH + u) * STRIDE);
  }

  auto phase = [&](int p, int slot) {
    if (wid == 0) {
      if (p <= NCHUNK - 1) {
        const int par = p & 1;
        asm volatile("s_waitcnt vmcnt(32)" ::: "memory");
        __builtin_amdgcn_sched_barrier(0);
        float xv[CH];
#pragma unroll
        for (int u = 0; u < CH; ++u) xv[u] = xbuf[slot][u][lane];
        __builtin_amdgcn_sched_barrier(0);
#pragma unroll
        for (int u = 0; u < CH; ++u) {
          float a = cbn;
          a = fmaf(QB(xv[u], 0), win[0], a);
          a = fmaf(QB(xv[u], 1), win[1], a);
          a = fmaf(QB(xv[u], 2), win[2], a);
          a = fmaf(QB(xv[u], 3), win[3], a);
          iface[0][par][u][lane] = a;
        }
#pragma unroll
        for (int u = 0; u < CH; ++u) {
          int tn = (p + 2) * CH + u;
          if (tn > TSTEPS - 1) tn = TSTEPS - 1;
          xload(&xbuf[(slot+2)%3][u][0], xp + (size_t)tn * STRIDE);
        }
      }
    } else {
      const int m = p - wid;
      if (m >= 0 && m <= NCHUNK - 1) {
        const int par = m & 1;
        float av[CH];
#pragma unroll
        for (int u = 0; u < CH; ++u) av[u] = iface[wid-1][par][u][lane];
        __builtin_amdgcn_sched_barrier(0);
        if (wid <= 2) {
#pragma unroll
          for (int u = 0; u < CH; ++u) {
            float t0 = fmaf(QB(r, 0), whp[0], av[u]);
            float t1 =      QB(r, 1) * whp[1];
            t0 = fmaf(QB(r, 2), whp[2], t0);
            t1 = fmaf(QB(r, 3), whp[3], t1);
            float e = fast_exp2(t0 + t1);
            r = fast_rcp(e + 1.0f);
            float h = fmaf(-2.0f, r, 1.0f);     // off-chain
            float a = cbn;
            a = fmaf(QB(h, 0), win[0], a);
            a = fmaf(QB(h, 1), win[1], a);
            a = fmaf(QB(h, 2), win[2], a);
            a = fmaf(QB(h, 3), win[3], a);
            iface[wid][par][u][lane] = a;
          }
        } else {
          const int base = m * CH;
#pragma unroll
          for (int u = 0; u < CH; ++u) {
            float t0 = fmaf(QB(r, 0), whp[0], av[u]);
            float t1 =      QB(r, 1) * whp[1];
            t0 = fmaf(QB(r, 2), whp[2], t0);
            t1 = fmaf(QB(r, 3), whp[3], t1);
            float e = fast_exp2(t0 + t1);
            r = fast_rcp(e + 1.0f);
            Y[(size_t)(base + u) * STRIDE + g] = fmaf(-2.0f, r, 1.0f);
          }
        }
      }
    }

    __builtin_amdgcn_sched_barrier(0);
    asm volatile("s_waitcnt lgkmcnt(0)" ::: "memory");
    __builtin_amdgcn_s_barrier();
    __builtin_amdgcn_sched_barrier(0);
  };

  for (int p = 0; p < NPH; p += 3) {
    phase(p + 0, 0);
    phase(p + 1, 1);
    phase(p + 2, 2);
  }

  if (wid == 0) asm volatile("s_waitcnt vmcnt(0)" ::: "memory");
}

// ====================== PROBES (timing only) ==============================
// Replica of the r18 T-wave inner machinery: per 32-step chunk, hoist av[32]
// from LDS, then 32 chain steps (4 DPP quad-dot -> exp2 -> add -> rcp) each
// with an off-chain ds_write of r. 4 waves/block on separate SIMDs (96 KB
// LDS -> 1 block/CU). BAR=0: no barriers (probeA). BAR=1: the exact r18
// phase-boundary sequence every chunk (probeB).
template <int BAR>
__global__ __launch_bounds__(256) void chain_probe(
    const float* __restrict__ X, float* __restrict__ ws, int do_store)
{
  const int lane = threadIdx.x & 63;
  const int w    = threadIdx.x >> 6;           // 0..3, one wave per SIMD
  const int idx  = (blockIdx.x * 256 + threadIdx.x) & 2047;

  __shared__ float av_l[4][CH][64];            // 32 KB ai source
  __shared__ float rb_l[4][2*CH][64];          // 64 KB r sink (padded->96 KB)

  // runtime weights (defeat constant folding); small values keep chain finite
  float w0 = X[idx]          * 0.25f;
  float w1 = X[idx + 2048]   * 0.25f;
  float w2 = X[idx + 4096]   * 0.25f;
  float w3 = X[idx + 6144]   * 0.25f;
  float r  = 0.25f + 0.001f * w0;

  // init av (finite inputs)
#pragma unroll
  for (int u = 0; u < CH; ++u) av_l[w][u][lane] = 0.125f * (u & 3) + w1;
  __builtin_amdgcn_s_barrier();

  for (int c = 0; c < PSTEPS / CH; ++c) {
    float av[CH];
#pragma unroll
    for (int u = 0; u < CH; ++u) av[u] = av_l[w][u][lane];
    __builtin_amdgcn_sched_barrier(0);
#pragma unroll
    for (int u = 0; u < CH; ++u) {
      float t0 = fmaf(QB(r, 0), w0, av[u]);
      float t1 =      QB(r, 1) * w1;
      t0 = fmaf(QB(r, 2), w2, t0);
      t1 = fmaf(QB(r, 3), w3, t1);
      r = fast_rcp(fast_exp2(t0 + t1) + 1.0f);
      rb_l[w][u][lane] = r;                    // off-chain ds_write
    }
    if (BAR) {
      __builtin_amdgcn_sched_barrier(0);
      asm volatile("s_waitcnt lgkmcnt(0)" ::: "memory");
      __builtin_amdgcn_s_barrier();
      __builtin_amdgcn_sched_barrier(0);
    }
  }
  asm volatile("" :: "v"(r));                  // keep chain live (rule #17)
  if (do_store) ws[(blockIdx.x * 256 + threadIdx.x) & 16383] = r + rb_l[w][0][lane];
}

extern "C" void kernel_launch(void* const* d_in, const int* in_sizes, int n_in,
                              void* d_out, int out_size, void* d_ws, size_t ws_size,
                              hipStream_t stream) {
  const float* X   = (const float*)d_in[0];
  const float* H0  = (const float*)d_in[1];
  const float* Wih = (const float*)d_in[2];
  const float* Whh = (const float*)d_in[3];
  const float* bih = (const float*)d_in[4];
  const float* bhh = (const float*)d_in[5];
  float* Y = (float*)d_out;

  // Production: 256 blocks x 256 threads (producer + 3 layer waves per CU).
  rnn_pipe4<<<dim3(STRIDE / 64), dim3(256), 0, stream>>>(X, H0, Wih, Whh, bih, bhh, Y);

  // Probes (timing only; write to scratch).
  int do_store = (ws_size >= 16384 * sizeof(float)) ? 1 : 0;
  chain_probe<0><<<dim3(256), dim3(256), 0, stream>>>(X, (float*)d_ws, do_store);
  chain_probe<1><<<dim3(256), dim3(256), 0, stream>>>(X, (float*)d_ws, do_store);
}

// Round 21
// 182.456 us; speedup vs baseline: 2.2800x; 2.2800x over previous
//
#include <hip/hip_runtime.h>

#define TSTEPS 2048
#define BATCH  4096
#define HID    4
#define STRIDE (BATCH*HID)    // 16384 floats per timestep slab
#define CH     32             // timesteps per chunk (barrier period)
#define NCHUNK (TSTEPS/CH)    // 64 source chunks
#define NPH    69             // T2 finishes chunk 63 at phase 68; 69 = 3*23

// Broadcast component k (0..3) to all 4 lanes of each quad via DPP quad_perm.
#define QB(v,k) __int_as_float(__builtin_amdgcn_update_dpp( \
    0, __float_as_int(v), (k)*0x55, 0xF, 0xF, true))

__device__ __forceinline__ float fast_exp2(float x) {
#if __has_builtin(__builtin_amdgcn_exp2f)
  return __builtin_amdgcn_exp2f(x);
#else
  return exp2f(x);
#endif
}
__device__ __forceinline__ float fast_rcp(float x) {
#if __has_builtin(__builtin_amdgcn_rcpf)
  return __builtin_amdgcn_rcpf(x);
#else
  return 1.0f / x;
#endif
}

// Direct global->LDS 4B load (wave-uniform LDS base + lane*4).
__device__ __forceinline__ void xload(float* ldst, const float* gsrc) {
  __builtin_amdgcn_global_load_lds(
      (const __attribute__((address_space(1))) void*)gsrc,
      (__attribute__((address_space(3))) void*)ldst, 4, 0, 0);
}

// Slim-chain 4-wave pipeline (r20 probes: chain+minimal-LDS = 106.5 cyc/step;
// barriers free among balanced waves; SIMD-sharing stretches chains).
//   wave 0 (P) : x staging + ALL ai production:
//                  ai0(p)   from x(p)          -> aif[0]
//                  ai1(p-2) from r0(p-2)       -> aif[1]
//                  ai2(p-4) from r1(p-4)       -> aif[2]
//   wave 1 (T0): chunk p-1: hoist aif[0] -> chain L0 -> rbuf[0]   (minimal)
//   wave 2 (T1): chunk p-3: hoist aif[1] -> chain L1 -> rbuf[1]   (minimal)
//   wave 3 (T2): chunk p-5: hoist aif[2] -> chain L2 -> Y         (minimal)
// Recurrence on r = 1/(1+exp2(a)), h = 1-2r folded into all weights:
//   T_l: a = av[u] + whp.quad(r),  whp = -2K*Whh[l]
//   P  : ai0 = K*(b0+Whh0.1) + (K*Wih0).quad(x)
//        ai_l = K*(b_l+Whh_l.1+Wih_l.1) + (-2K*Wih_l).quad(r_{l-1}), l=1,2
// Protocol (r9/r15-verified): double-buffered LDS by chunk parity (every
// parity slot rewritten 2 phases after its read -> race-free), ONE raw
// s_barrier per phase, lgkmcnt(0) drained before it, vmcnt counted (32) on P
// only, never drained in-loop.
__global__ __launch_bounds__(256) void rnn_slim(
    const float* __restrict__ X,    // (T, B, H)
    const float* __restrict__ H0,   // (L, B, H)
    const float* __restrict__ Wih,  // (L, H, H)
    const float* __restrict__ Whh,  // (L, H, H)
    const float* __restrict__ bih,  // (L, H)
    const float* __restrict__ bhh,  // (L, H)
    float* __restrict__ Y)          // (T, B, H)
{
  const int lane = threadIdx.x & 63;
  const int w    = threadIdx.x >> 6;           // 0 = P; 1..3 = T0..T2
  const int g    = blockIdx.x * 64 + lane;     // global (b,j) unit
  const int j    = g & 3;
  const float K  = 2.8853900817779268f;        // 2*log2(e)

  __shared__ float xbuf[3][CH][64];            // 24 KB x staging ring
  __shared__ float aif[3][2][CH][64];          // 48 KB ai handoff P -> T_l
  __shared__ float rbuf[2][2][CH][64];         // 32 KB r handoff T_l -> P

  // Per-wave weights.
  float wipA[3][HID], cbA[3];                  // P only
  float whp[HID];                              // T only
  float r = 0.0f;
  if (w == 0) {
#pragma unroll
    for (int l = 0; l < 3; ++l) {
      float wsum = 0.0f, isum = 0.0f;
#pragma unroll
      for (int k = 0; k < HID; ++k) {
        float wik = Wih[(l*HID + j)*HID + k];
        wipA[l][k] = (l == 0) ? (K * wik) : (-2.0f * K * wik);
        wsum += Whh[(l*HID + j)*HID + k];
        isum += wik;
      }
      cbA[l] = K * (bih[l*HID + j] + bhh[l*HID + j] + wsum
                    + ((l == 0) ? 0.0f : isum));
    }
  } else {
    const int Lt = w - 1;
#pragma unroll
    for (int k = 0; k < HID; ++k)
      whp[k] = -2.0f * K * Whh[(Lt*HID + j)*HID + k];
    r = 0.5f * (1.0f - H0[Lt*STRIDE + g]);     // h = 1 - 2r
  }

  const float* __restrict__ xp = X + g;

  // Prime the x pipeline: chunks 0,1 -> slots 0,1 (64 outstanding loads).
  if (w == 0) {
    __builtin_amdgcn_sched_barrier(0);
    asm volatile("s_waitcnt vmcnt(0)" ::: "memory");  // clean vmcnt baseline
#pragma unroll
    for (int u = 0; u < CH; ++u)
      xload(&xbuf[0][u][0], xp + (size_t)(0*CH + u) * STRIDE);
#pragma unroll
    for (int u = 0; u < CH; ++u)
      xload(&xbuf[1][u][0], xp + (size_t)(1*CH + u) * STRIDE);
  }

  auto phase = [&](int p, int slot) {
    if (w == 0) {
      // --- ai0 from x (chunk p) ---
      if (p <= NCHUNK - 1) {
        const int par = p & 1;
        asm volatile("s_waitcnt vmcnt(32)" ::: "memory");
        __builtin_amdgcn_sched_barrier(0);
        float xv[CH];
#pragma unroll
        for (int u = 0; u < CH; ++u) xv[u] = xbuf[slot][u][lane];
        __builtin_amdgcn_sched_barrier(0);
#pragma unroll
        for (int u = 0; u < CH; ++u) {
          float a = cbA[0];
          a = fmaf(QB(xv[u], 0), wipA[0][0], a);
          a = fmaf(QB(xv[u], 1), wipA[0][1], a);
          a = fmaf(QB(xv[u], 2), wipA[0][2], a);
          a = fmaf(QB(xv[u], 3), wipA[0][3], a);
          aif[0][par][u][lane] = a;
        }
        // refill chunk p+2 -> slot (slot+2)%3; always 32 issues (clamped
        // tail loads land but are never consumed -> vmcnt invariant exact)
#pragma unroll
        for (int u = 0; u < CH; ++u) {
          int tn = (p + 2) * CH + u;
          if (tn > TSTEPS - 1) tn = TSTEPS - 1;
          xload(&xbuf[(slot+2)%3][u][0], xp + (size_t)tn * STRIDE);
        }
      }
      // --- ai1 from r0 (chunk p-2) ---
      const int m1 = p - 2;
      if (m1 >= 0 && m1 <= NCHUNK - 1) {
        const int par = m1 & 1;
        float rv[CH];
#pragma unroll
        for (int u = 0; u < CH; ++u) rv[u] = rbuf[0][par][u][lane];
        __builtin_amdgcn_sched_barrier(0);
#pragma unroll
        for (int u = 0; u < CH; ++u) {
          float a = cbA[1];
          a = fmaf(QB(rv[u], 0), wipA[1][0], a);
          a = fmaf(QB(rv[u], 1), wipA[1][1], a);
          a = fmaf(QB(rv[u], 2), wipA[1][2], a);
          a = fmaf(QB(rv[u], 3), wipA[1][3], a);
          aif[1][par][u][lane] = a;
        }
      }
      // --- ai2 from r1 (chunk p-4) ---
      const int m2 = p - 4;
      if (m2 >= 0 && m2 <= NCHUNK - 1) {
        const int par = m2 & 1;
        float rv[CH];
#pragma unroll
        for (int u = 0; u < CH; ++u) rv[u] = rbuf[1][par][u][lane];
        __builtin_amdgcn_sched_barrier(0);
#pragma unroll
        for (int u = 0; u < CH; ++u) {
          float a = cbA[2];
          a = fmaf(QB(rv[u], 0), wipA[2][0], a);
          a = fmaf(QB(rv[u], 1), wipA[2][1], a);
          a = fmaf(QB(rv[u], 2), wipA[2][2], a);
          a = fmaf(QB(rv[u], 3), wipA[2][3], a);
          aif[2][par][u][lane] = a;
        }
      }
    } else {
      // --- minimal chain wave: hoist -> chain -> (rbuf | Y) ---
      const int m = p - (2*w - 1);             // T0: p-1, T1: p-3, T2: p-5
      if (m >= 0 && m <= NCHUNK - 1) {
        const int par = m & 1;
        float av[CH];
#pragma unroll
        for (int u = 0; u < CH; ++u) av[u] = aif[w-1][par][u][lane];
        __builtin_amdgcn_sched_barrier(0);
        if (w <= 2) {
#pragma unroll
          for (int u = 0; u < CH; ++u) {
            float t0 = fmaf(QB(r, 0), whp[0], av[u]);
            float t1 =      QB(r, 1) * whp[1];
            t0 = fmaf(QB(r, 2), whp[2], t0);
            t1 = fmaf(QB(r, 3), whp[3], t1);
            r = fast_rcp(fast_exp2(t0 + t1) + 1.0f);
            rbuf[w-1][par][u][lane] = r;       // off-chain store
          }
        } else {
          const int base = m * CH;
#pragma unroll
          for (int u = 0; u < CH; ++u) {
            float t0 = fmaf(QB(r, 0), whp[0], av[u]);
            float t1 =      QB(r, 1) * whp[1];
            t0 = fmaf(QB(r, 2), whp[2], t0);
            t1 = fmaf(QB(r, 3), whp[3], t1);
            r = fast_rcp(fast_exp2(t0 + t1) + 1.0f);
            Y[(size_t)(base + u) * STRIDE + g] = fmaf(-2.0f, r, 1.0f);
          }
        }
      }
    }

    // phase boundary: drain LDS ops only (NOT vmcnt), then raw barrier.
    __builtin_amdgcn_sched_barrier(0);
    asm volatile("s_waitcnt lgkmcnt(0)" ::: "memory");
    __builtin_amdgcn_s_barrier();
    __builtin_amdgcn_sched_barrier(0);
  };

  for (int p = 0; p < NPH; p += 3) {   // 69 = 3 * 23, static xbuf slots
    phase(p + 0, 0);
    phase(p + 1, 1);
    phase(p + 2, 2);
  }

  // drain outstanding (clamped-tail) staging loads before LDS dealloc
  if (w == 0) asm volatile("s_waitcnt vmcnt(0)" ::: "memory");
}

extern "C" void kernel_launch(void* const* d_in, const int* in_sizes, int n_in,
                              void* d_out, int out_size, void* d_ws, size_t ws_size,
                              hipStream_t stream) {
  const float* X   = (const float*)d_in[0];
  const float* H0  = (const float*)d_in[1];
  const float* Wih = (const float*)d_in[2];
  const float* Whh = (const float*)d_in[3];
  const float* bih = (const float*)d_in[4];
  const float* bhh = (const float*)d_in[5];
  float* Y = (float*)d_out;

  // 256 blocks x 256 threads: 1 producer + 3 solo chain waves per CU.
  rnn_slim<<<dim3(STRIDE / 64), dim3(256), 0, stream>>>(X, H0, Wih, Whh, bih, bhh, Y);
}

// Round 22
// 106.382 us; speedup vs baseline: 3.9105x; 1.7151x over previous
//
#include <hip/hip_runtime.h>

#define TSTEPS 2048
#define BATCH  4096
#define HID    4
#define STRIDE (BATCH*HID)    // 16384 floats per timestep slab
#define CH     32             // timesteps per chunk (barrier period)
#define NCHUNK (TSTEPS/CH)    // 64 source chunks
#define NPH    69             // >= NCHUNK+4, = 3*23 for static slot rotation

// Broadcast component k (0..3) to all 4 lanes of each quad via DPP quad_perm.
#define QB(v,k) __int_as_float(__builtin_amdgcn_update_dpp( \
    0, __float_as_int(v), (k)*0x55, 0xF, 0xF, true))

__device__ __forceinline__ float fast_exp2(float x) {
#if __has_builtin(__builtin_amdgcn_exp2f)
  return __builtin_amdgcn_exp2f(x);
#else
  return exp2f(x);
#endif
}
__device__ __forceinline__ float fast_rcp(float x) {
#if __has_builtin(__builtin_amdgcn_rcpf)
  return __builtin_amdgcn_rcpf(x);
#else
  return 1.0f / x;
#endif
}

// Direct global->LDS 4B load (wave-uniform LDS base + lane*4).
__device__ __forceinline__ void xload(float* ldst, const float* gsrc) {
  __builtin_amdgcn_global_load_lds(
      (const __attribute__((address_space(1))) void*)gsrc,
      (__attribute__((address_space(3))) void*)ldst, 4, 0, 0);
}

// r15 topology (115us, best) + DPP-sharing issue-diet on the T-waves
// (fold verified on-HW in r16). Structure, staging, barriers identical
// to r15; ONLY the T-wave inner loop changed.
//   wave 0 (P) : x staging + ai0 -> iface[0]
//   wave 1 (T1): chain L0 + DPP-shared ai1 -> iface[1]
//   wave 2 (T2): chain L1 + DPP-shared ai2 -> iface[2]
//   wave 3 (T3): chain L2 + Y store
// Recurrence on r = 1/(1+exp2(a)), h = 1-2r folded into ALL weights:
//   chain: a = av[u] + whp.quad(r),  whp = -2K*Whh[l]
//   ai-production consumes the SAME quad(r): wip = -2K*Wih[l+1],
//   cbn = K*(b[l+1] + Whh[l+1].1 + Wih[l+1].1); ai(u) emitted in step u+1
//   (uses step u+1's DPPs of r_u), epilogue emits ai(CH-1).
// Protocol: double-buffered ifaces (par = m&1), ONE raw s_barrier per phase,
// lgkmcnt(0) drained before it, vmcnt counted (32), never drained in-loop.
__global__ __launch_bounds__(256) void rnn_pipe4(
    const float* __restrict__ X,    // (T, B, H)
    const float* __restrict__ H0,   // (L, B, H)
    const float* __restrict__ Wih,  // (L, H, H)
    const float* __restrict__ Whh,  // (L, H, H)
    const float* __restrict__ bih,  // (L, H)
    const float* __restrict__ bhh,  // (L, H)
    float* __restrict__ Y)          // (T, B, H)
{
  const int lane = threadIdx.x & 63;
  const int wid  = threadIdx.x >> 6;           // 0 = producer; 1..3 = layers
  const int g    = blockIdx.x * 64 + lane;     // global (b,j) unit
  const int j    = g & 3;
  const float K  = 2.8853900817779268f;        // 2*log2(e)

  __shared__ float iface[3][2][CH][64];        // 48 KB: ai handoff l -> l+1
  __shared__ float xbuf[3][CH][64];            // 24 KB: x staging ring

  float whp[HID], wip[HID], cbn = 0.0f, r = 0.0f;
  {
    const int Lt = wid - 1;                    // tail layer
    const int Ln = wid;                        // next-ai layer
    if (wid >= 1) {
#pragma unroll
      for (int k = 0; k < HID; ++k)
        whp[k] = -2.0f * K * Whh[(Lt*HID + j)*HID + k];
      r = 0.5f * (1.0f - H0[Lt*STRIDE + g]);   // h = 1 - 2r
    }
    if (wid == 0) {                            // ai0 from raw x
      float wsum = 0.0f;
#pragma unroll
      for (int k = 0; k < HID; ++k) {
        wip[k] = K * Wih[(Ln*HID + j)*HID + k];
        wsum  += Whh[(Ln*HID + j)*HID + k];
      }
      cbn = K * (bih[Ln*HID + j] + bhh[Ln*HID + j] + wsum);
    } else if (wid <= 2) {                     // ai(l+1) from quad(r), folded
      float wsum = 0.0f;
#pragma unroll
      for (int k = 0; k < HID; ++k) {
        float wik = Wih[(Ln*HID + j)*HID + k];
        wip[k] = -2.0f * K * wik;
        wsum  += Whh[(Ln*HID + j)*HID + k] + wik;
      }
      cbn = K * (bih[Ln*HID + j] + bhh[Ln*HID + j] + wsum);
    }
  }

  const float* __restrict__ xp = X + g;

  if (wid == 0) {
    __builtin_amdgcn_sched_barrier(0);
    asm volatile("s_waitcnt vmcnt(0)" ::: "memory");
#pragma unroll
    for (int u = 0; u < CH; ++u)
      xload(&xbuf[0][u][0], xp + (size_t)(0*CH + u) * STRIDE);
#pragma unroll
    for (int u = 0; u < CH; ++u)
      xload(&xbuf[1][u][0], xp + (size_t)(1*CH + u) * STRIDE);
  }

  auto phase = [&](int p, int slot) {
    if (wid == 0) {
      if (p <= NCHUNK - 1) {
        const int par = p & 1;
        asm volatile("s_waitcnt vmcnt(32)" ::: "memory");
        __builtin_amdgcn_sched_barrier(0);
        float xv[CH];
#pragma unroll
        for (int u = 0; u < CH; ++u) xv[u] = xbuf[slot][u][lane];
        __builtin_amdgcn_sched_barrier(0);
#pragma unroll
        for (int u = 0; u < CH; ++u) {
          float a = cbn;
          a = fmaf(QB(xv[u], 0), wip[0], a);
          a = fmaf(QB(xv[u], 1), wip[1], a);
          a = fmaf(QB(xv[u], 2), wip[2], a);
          a = fmaf(QB(xv[u], 3), wip[3], a);
          iface[0][par][u][lane] = a;
        }
#pragma unroll
        for (int u = 0; u < CH; ++u) {
          int tn = (p + 2) * CH + u;
          if (tn > TSTEPS - 1) tn = TSTEPS - 1;
          xload(&xbuf[(slot+2)%3][u][0], xp + (size_t)tn * STRIDE);
        }
      }
    } else {
      const int m = p - wid;
      if (m >= 0 && m <= NCHUNK - 1) {
        const int par = m & 1;
        float av[CH];
#pragma unroll
        for (int u = 0; u < CH; ++u) av[u] = iface[wid-1][par][u][lane];
        __builtin_amdgcn_sched_barrier(0);
        if (wid <= 2) {
          // chain + DPP-shared delayed ai (r16-verified fold)
#pragma unroll
          for (int u = 0; u < CH; ++u) {
            float d0 = QB(r, 0), d1 = QB(r, 1), d2 = QB(r, 2), d3 = QB(r, 3);
            if (u > 0) {                        // ai(u-1) from quad(r_{u-1})
              float a = cbn;
              a = fmaf(d0, wip[0], a);
              a = fmaf(d1, wip[1], a);
              a = fmaf(d2, wip[2], a);
              a = fmaf(d3, wip[3], a);
              iface[wid][par][u-1][lane] = a;
            }
            float t0 = fmaf(d0, whp[0], av[u]);
            float t1 = d1 * whp[1];
            t0 = fmaf(d2, whp[2], t0);
            t1 = fmaf(d3, whp[3], t1);
            r = fast_rcp(fast_exp2(t0 + t1) + 1.0f);
          }
          {                                     // epilogue: ai(CH-1)
            float d0 = QB(r, 0), d1 = QB(r, 1), d2 = QB(r, 2), d3 = QB(r, 3);
            float a = cbn;
            a = fmaf(d0, wip[0], a);
            a = fmaf(d1, wip[1], a);
            a = fmaf(d2, wip[2], a);
            a = fmaf(d3, wip[3], a);
            iface[wid][par][CH-1][lane] = a;
          }
        } else {
          const int base = m * CH;              // final layer: chain + Y
#pragma unroll
          for (int u = 0; u < CH; ++u) {
            float t0 = fmaf(QB(r, 0), whp[0], av[u]);
            float t1 =      QB(r, 1) * whp[1];
            t0 = fmaf(QB(r, 2), whp[2], t0);
            t1 = fmaf(QB(r, 3), whp[3], t1);
            r = fast_rcp(fast_exp2(t0 + t1) + 1.0f);
            Y[(size_t)(base + u) * STRIDE + g] = fmaf(-2.0f, r, 1.0f);
          }
        }
      }
    }

    __builtin_amdgcn_sched_barrier(0);
    asm volatile("s_waitcnt lgkmcnt(0)" ::: "memory");
    __builtin_amdgcn_s_barrier();
    __builtin_amdgcn_sched_barrier(0);
  };

  for (int p = 0; p < NPH; p += 3) {
    phase(p + 0, 0);
    phase(p + 1, 1);
    phase(p + 2, 2);
  }

  if (wid == 0) asm volatile("s_waitcnt vmcnt(0)" ::: "memory");
}

extern "C" void kernel_launch(void* const* d_in, const int* in_sizes, int n_in,
                              void* d_out, int out_size, void* d_ws, size_t ws_size,
                              hipStream_t stream) {
  const float* X   = (const float*)d_in[0];
  const float* H0  = (const float*)d_in[1];
  const float* Wih = (const float*)d_in[2];
  const float* Whh = (const float*)d_in[3];
  const float* bih = (const float*)d_in[4];
  const float* bhh = (const float*)d_in[5];
  float* Y = (float*)d_out;

  // 256 blocks x 256 threads: producer + 3 layer waves per CU.
  rnn_pipe4<<<dim3(STRIDE / 64), dim3(256), 0, stream>>>(X, H0, Wih, Whh, bih, bhh, Y);
}

// Round 23
// 102.708 us; speedup vs baseline: 4.0504x; 1.0358x over previous
//
#include <hip/hip_runtime.h>

#define TSTEPS 2048
#define BATCH  4096
#define HID    4
#define STRIDE (BATCH*HID)    // 16384 floats per timestep slab
#define CH     32             // timesteps per chunk (barrier period)
#define NCHUNK (TSTEPS/CH)    // 64 source chunks
#define NPH    69             // >= NCHUNK+4, = 3*23 for static slot rotation

// Broadcast component k (0..3) to all 4 lanes of each quad via DPP quad_perm.
#define QB(v,k) __int_as_float(__builtin_amdgcn_update_dpp( \
    0, __float_as_int(v), (k)*0x55, 0xF, 0xF, true))

__device__ __forceinline__ float fast_exp2(float x) {
#if __has_builtin(__builtin_amdgcn_exp2f)
  return __builtin_amdgcn_exp2f(x);
#else
  return exp2f(x);
#endif
}
__device__ __forceinline__ float fast_rcp(float x) {
#if __has_builtin(__builtin_amdgcn_rcpf)
  return __builtin_amdgcn_rcpf(x);
#else
  return 1.0f / x;
#endif
}

// Direct global->LDS 4B load (wave-uniform LDS base + lane*4).
__device__ __forceinline__ void xload(float* ldst, const float* gsrc) {
  __builtin_amdgcn_global_load_lds(
      (const __attribute__((address_space(1))) void*)gsrc,
      (__attribute__((address_space(3))) void*)ldst, 4, 0, 0);
}

// r22 winner (106.4us) + b64-paired iface handoffs (single change).
// iface layout: [l][par][pair][lane][2] -> consecutive steps adjacent per
// lane: hoist = 16 ds_read_b64 (was 32 b32, ~90 cyc/chunk saved), writes =
// 16 ds_write_b64 (ai buffered one step, epilogue completes last pair).
// Bank: addr/4 = pair*128 + lane*2 + half -> 2 lanes/bank = free (m136).
//   wave 0 (P) : x staging + ai0 (paired writes) -> iface[0]
//   wave 1 (T1): chain L0 + DPP-shared ai1 (paired) -> iface[1]
//   wave 2 (T2): chain L1 + DPP-shared ai2 (paired) -> iface[2]
//   wave 3 (T3): chain L2 + Y store (scalar global)
// Recurrence on r = 1/(1+exp2(a)), h = 1-2r folded into ALL weights:
//   chain: a = av[u] + whp.quad(r),  whp = -2K*Whh[l]
//   ai consumes the SAME quad(r): wip = -2K*Wih[l+1],
//   cbn = K*(b[l+1] + Whh[l+1].1 + Wih[l+1].1).
// Protocol: double-buffered ifaces (par = m&1), ONE raw s_barrier per phase,
// lgkmcnt(0) drained before it, vmcnt counted (32), never drained in-loop.
__global__ __launch_bounds__(256) void rnn_pipe4(
    const float* __restrict__ X,    // (T, B, H)
    const float* __restrict__ H0,   // (L, B, H)
    const float* __restrict__ Wih,  // (L, H, H)
    const float* __restrict__ Whh,  // (L, H, H)
    const float* __restrict__ bih,  // (L, H)
    const float* __restrict__ bhh,  // (L, H)
    float* __restrict__ Y)          // (T, B, H)
{
  const int lane = threadIdx.x & 63;
  const int wid  = threadIdx.x >> 6;           // 0 = producer; 1..3 = layers
  const int g    = blockIdx.x * 64 + lane;     // global (b,j) unit
  const int j    = g & 3;
  const float K  = 2.8853900817779268f;        // 2*log2(e)

  __shared__ float iface[3][2][CH/2][64][2];   // 48 KB, b64-paired handoff
  __shared__ float xbuf[3][CH][64];            // 24 KB: x staging ring

  float whp[HID], wip[HID], cbn = 0.0f, r = 0.0f;
  {
    const int Lt = wid - 1;                    // tail layer
    const int Ln = wid;                        // next-ai layer
    if (wid >= 1) {
#pragma unroll
      for (int k = 0; k < HID; ++k)
        whp[k] = -2.0f * K * Whh[(Lt*HID + j)*HID + k];
      r = 0.5f * (1.0f - H0[Lt*STRIDE + g]);   // h = 1 - 2r
    }
    if (wid == 0) {                            // ai0 from raw x
      float wsum = 0.0f;
#pragma unroll
      for (int k = 0; k < HID; ++k) {
        wip[k] = K * Wih[(Ln*HID + j)*HID + k];
        wsum  += Whh[(Ln*HID + j)*HID + k];
      }
      cbn = K * (bih[Ln*HID + j] + bhh[Ln*HID + j] + wsum);
    } else if (wid <= 2) {                     // ai(l+1) from quad(r), folded
      float wsum = 0.0f;
#pragma unroll
      for (int k = 0; k < HID; ++k) {
        float wik = Wih[(Ln*HID + j)*HID + k];
        wip[k] = -2.0f * K * wik;
        wsum  += Whh[(Ln*HID + j)*HID + k] + wik;
      }
      cbn = K * (bih[Ln*HID + j] + bhh[Ln*HID + j] + wsum);
    }
  }

  const float* __restrict__ xp = X + g;

  if (wid == 0) {
    __builtin_amdgcn_sched_barrier(0);
    asm volatile("s_waitcnt vmcnt(0)" ::: "memory");
#pragma unroll
    for (int u = 0; u < CH; ++u)
      xload(&xbuf[0][u][0], xp + (size_t)(0*CH + u) * STRIDE);
#pragma unroll
    for (int u = 0; u < CH; ++u)
      xload(&xbuf[1][u][0], xp + (size_t)(1*CH + u) * STRIDE);
  }

  auto phase = [&](int p, int slot) {
    if (wid == 0) {
      if (p <= NCHUNK - 1) {
        const int par = p & 1;
        asm volatile("s_waitcnt vmcnt(32)" ::: "memory");
        __builtin_amdgcn_sched_barrier(0);
        float xv[CH];
#pragma unroll
        for (int u = 0; u < CH; ++u) xv[u] = xbuf[slot][u][lane];
        __builtin_amdgcn_sched_barrier(0);
        float apend = 0.0f;
#pragma unroll
        for (int u = 0; u < CH; ++u) {
          float a = cbn;
          a = fmaf(QB(xv[u], 0), wip[0], a);
          a = fmaf(QB(xv[u], 1), wip[1], a);
          a = fmaf(QB(xv[u], 2), wip[2], a);
          a = fmaf(QB(xv[u], 3), wip[3], a);
          if (u & 1) {
            float2 pr = {apend, a};
            *(float2*)&iface[0][par][u >> 1][lane][0] = pr;
          } else {
            apend = a;
          }
        }
#pragma unroll
        for (int u = 0; u < CH; ++u) {
          int tn = (p + 2) * CH + u;
          if (tn > TSTEPS - 1) tn = TSTEPS - 1;
          xload(&xbuf[(slot+2)%3][u][0], xp + (size_t)tn * STRIDE);
        }
      }
    } else {
      const int m = p - wid;
      if (m >= 0 && m <= NCHUNK - 1) {
        const int par = m & 1;
        float av[CH];
#pragma unroll
        for (int p2 = 0; p2 < CH/2; ++p2) {
          float2 v = *(const float2*)&iface[wid-1][par][p2][lane][0];
          av[2*p2]   = v.x;
          av[2*p2+1] = v.y;
        }
        __builtin_amdgcn_sched_barrier(0);
        if (wid <= 2) {
          // chain + DPP-shared ai, b64-paired writes (ai(u-1) at step u;
          // pairs {ai(u-2),ai(u-1)} written at even u; epilogue last pair)
          float apend = 0.0f;
#pragma unroll
          for (int u = 0; u < CH; ++u) {
            float d0 = QB(r, 0), d1 = QB(r, 1), d2 = QB(r, 2), d3 = QB(r, 3);
            if (u > 0) {
              float a = cbn;
              a = fmaf(d0, wip[0], a);
              a = fmaf(d1, wip[1], a);
              a = fmaf(d2, wip[2], a);
              a = fmaf(d3, wip[3], a);
              if (u & 1) {                      // u odd: ai(u-1) even -> hold
                apend = a;
              } else {                          // u even: write {ai(u-2),ai(u-1)}
                float2 pr = {apend, a};
                *(float2*)&iface[wid][par][(u-2) >> 1][lane][0] = pr;
              }
            }
            float t0 = fmaf(d0, whp[0], av[u]);
            float t1 = d1 * whp[1];
            t0 = fmaf(d2, whp[2], t0);
            t1 = fmaf(d3, whp[3], t1);
            r = fast_rcp(fast_exp2(t0 + t1) + 1.0f);
          }
          {                                     // epilogue: {ai(30), ai(31)}
            float d0 = QB(r, 0), d1 = QB(r, 1), d2 = QB(r, 2), d3 = QB(r, 3);
            float a = cbn;
            a = fmaf(d0, wip[0], a);
            a = fmaf(d1, wip[1], a);
            a = fmaf(d2, wip[2], a);
            a = fmaf(d3, wip[3], a);
            float2 pr = {apend, a};
            *(float2*)&iface[wid][par][(CH-2) >> 1][lane][0] = pr;
          }
        } else {
          const int base = m * CH;              // final layer: chain + Y
#pragma unroll
          for (int u = 0; u < CH; ++u) {
            float t0 = fmaf(QB(r, 0), whp[0], av[u]);
            float t1 =      QB(r, 1) * whp[1];
            t0 = fmaf(QB(r, 2), whp[2], t0);
            t1 = fmaf(QB(r, 3), whp[3], t1);
            r = fast_rcp(fast_exp2(t0 + t1) + 1.0f);
            Y[(size_t)(base + u) * STRIDE + g] = fmaf(-2.0f, r, 1.0f);
          }
        }
      }
    }

    __builtin_amdgcn_sched_barrier(0);
    asm volatile("s_waitcnt lgkmcnt(0)" ::: "memory");
    __builtin_amdgcn_s_barrier();
    __builtin_amdgcn_sched_barrier(0);
  };

  for (int p = 0; p < NPH; p += 3) {
    phase(p + 0, 0);
    phase(p + 1, 1);
    phase(p + 2, 2);
  }

  if (wid == 0) asm volatile("s_waitcnt vmcnt(0)" ::: "memory");
}

extern "C" void kernel_launch(void* const* d_in, const int* in_sizes, int n_in,
                              void* d_out, int out_size, void* d_ws, size_t ws_size,
                              hipStream_t stream) {
  const float* X   = (const float*)d_in[0];
  const float* H0  = (const float*)d_in[1];
  const float* Wih = (const float*)d_in[2];
  const float* Whh = (const float*)d_in[3];
  const float* bih = (const float*)d_in[4];
  const float* bhh = (const float*)d_in[5];
  float* Y = (float*)d_out;

  // 256 blocks x 256 threads: producer + 3 layer waves per CU.
  rnn_pipe4<<<dim3(STRIDE / 64), dim3(256), 0, stream>>>(X, H0, Wih, Whh, bih, bhh, Y);
}